// Round 1
// 1383.519 us; speedup vs baseline: 1.3160x; 1.3160x over previous
//
#include <hip/hip_runtime.h>
#include <hip/hip_bf16.h>

// Problem constants (fixed by the reference): B=4 H=16 L=2048 D=64, temp=8.0
#define Bb 4
#define Hh 16
#define Ll 2048
#define Dd 64
#define MT 64              // query rows per workgroup (16 per wave)

// old (fallback) kernel chunking
#define KC 128
#define NCH (Ll / KC)      // 16

// new kernel chunking
#define KB2 64
#define NB2 (Ll / KB2)     // 32

// exp(x*0.125) == exp2(x * 0.125*log2(e))
#define EXPSC 0.18033688011112042f

typedef float f32x4 __attribute__((ext_vector_type(4)));
typedef short s16x8 __attribute__((ext_vector_type(8)));

// round-to-nearest-even fp32 -> bf16 (finite inputs only)
static __device__ __forceinline__ short f2bf(float f) {
  unsigned u = __builtin_bit_cast(unsigned, f);
  u += 0x7fff + ((u >> 16) & 1);
  return (short)(u >> 16);
}

// async global->LDS, 16B per lane; LDS dest must be wave-uniform base (HW adds lane*16)
static __device__ __forceinline__ void gld_lds16(const void* g, void* l) {
  __builtin_amdgcn_global_load_lds(
      (const __attribute__((address_space(1))) unsigned int*)g,
      (__attribute__((address_space(3))) unsigned int*)l, 16, 0, 0);
}

// ===================== pre-kernel 1: K fp32 -> bf16, bank-swizzled =====================
// Kb[row][colblk8]: physical 8-short block jp holds logical block jp ^ (l&7)
__global__ __launch_bounds__(256) void prep_k(const float* __restrict__ K,
                                              short* __restrict__ Kb) {
  int i = blockIdx.x * 256 + threadIdx.x;   // 0 .. B*H*L*8-1
  int row = i >> 3;                         // global row bh*L + l   (row&7 == l&7)
  int j = i & 7;
  const float* src = K + ((size_t)row << 6) + (j << 3);
  float4 a = *(const float4*)src;
  float4 b = *(const float4*)(src + 4);
  s16x8 o;
  o[0] = f2bf(a.x); o[1] = f2bf(a.y); o[2] = f2bf(a.z); o[3] = f2bf(a.w);
  o[4] = f2bf(b.x); o[5] = f2bf(b.y); o[6] = f2bf(b.z); o[7] = f2bf(b.w);
  int jp = j ^ (row & 7);
  *(s16x8*)(Kb + ((size_t)row << 6) + (jp << 3)) = o;
}

// ============ pre-kernel 2: V fp32 [k][d] -> bf16 transposed [d][k], swizzled ==========
// Within each 64-k chunk: physical 8-short block pb holds logical block pb ^ (d&7)
__global__ __launch_bounds__(256) void prep_v(const float* __restrict__ V,
                                              short* __restrict__ Vtb) {
  __shared__ float T[64][65];
  int bh = blockIdx.x >> 5, kt = blockIdx.x & 31;
  int t = threadIdx.x;
  const float* src = V + (((size_t)bh * Ll + kt * 64) << 6);
  {
    int kr = t >> 2;
    int c0 = (t & 3) << 4;
#pragma unroll
    for (int p = 0; p < 4; ++p) {
      float4 v = *(const float4*)(src + kr * 64 + c0 + p * 4);
      T[kr][c0 + p * 4 + 0] = v.x; T[kr][c0 + p * 4 + 1] = v.y;
      T[kr][c0 + p * 4 + 2] = v.z; T[kr][c0 + p * 4 + 3] = v.w;
    }
  }
  __syncthreads();
  int d = t >> 2;
  int kb = (t & 3) << 4;   // 16 logical k per thread
  short* dst = Vtb + (((size_t)bh * 64 + d) << 11) + (kt << 6);
  s16x8 o0, o1;
#pragma unroll
  for (int i2 = 0; i2 < 8; ++i2) {
    o0[i2] = f2bf(T[kb + i2][d]);
    o1[i2] = f2bf(T[kb + 8 + i2][d]);
  }
  int b0 = (kb >> 3) ^ (d & 7);
  int b1 = ((kb >> 3) + 1) ^ (d & 7);
  *(s16x8*)(dst + (b0 << 3)) = o0;
  *(s16x8*)(dst + (b1 << 3)) = o1;
}

// ===================== main kernel: async-staged, double-buffered =====================
__global__ __launch_bounds__(256) void sdpa_fused2(
    const float* __restrict__ Qg, const short* __restrict__ Kb,
    const short* __restrict__ Vb, const unsigned char* __restrict__ Mg,
    float* __restrict__ out) {
  __shared__ short Ks[2][KB2][64];   // 16384 B, linear (global pre-swizzled)
  __shared__ short Vt[2][64][KB2];   // 16384 B, linear (global pre-swizzled)
  __shared__ short Pt[4][16][40];    //  5120 B, per-wave P C->A layout bounce

  const int tid  = threadIdx.x;
  const int w    = tid >> 6;
  const int lane = tid & 63;
  const int m    = lane & 15;
  const int quad = lane >> 4;

  const int bh = blockIdx.x >> 5;    // b*16 + h
  const int qt = blockIdx.x & 31;
  const int b  = bh >> 4;
  const int q0 = qt * MT;
  const int rowb = q0 + w * 16;

  const float* Qh = Qg + (size_t)bh * Ll * Dd;
  const short* Kh = Kb + (size_t)bh * Ll * Dd;
  const short* Vh = Vb + (size_t)bh * Dd * Ll;   // [d][l]
  const unsigned char* Mb = Mg + (size_t)b * Ll * Ll;
  float* res = out + (size_t)bh * Ll * Dd;
  float* att = out + (size_t)Bb * Hh * Ll * Dd + (size_t)bh * Ll * Ll;

  // persistent Q fragments: lane holds Q[rowb+m][k = s*32 + quad*8 + j]
  s16x8 qf[2];
  {
    const float* qp = Qh + (size_t)(rowb + m) * Dd + quad * 8;
#pragma unroll
    for (int s = 0; s < 2; ++s) {
      float4 a = *(const float4*)(qp + s * 32);
      float4 c = *(const float4*)(qp + s * 32 + 4);
      qf[s][0] = f2bf(a.x); qf[s][1] = f2bf(a.y);
      qf[s][2] = f2bf(a.z); qf[s][3] = f2bf(a.w);
      qf[s][4] = f2bf(c.x); qf[s][5] = f2bf(c.y);
      qf[s][6] = f2bf(c.z); qf[s][7] = f2bf(c.w);
    }
  }

  const int sw = (m & 7) << 3;             // read-side XOR swizzle (shorts)
  const int mrow = rowb + (lane >> 2);     // mask prefetch: wave's own 16 rows
  const int mcol = (lane & 3) << 4;
  uint4 mpre;

  auto stageK = [&](int ch, int buf) {
    const char* s = (const char*)(Kh + (size_t)ch * KB2 * Dd);
    char* d0 = (char*)&Ks[buf][0][0];
#pragma unroll
    for (int c = 0; c < 2; ++c) {
      int off = (w * 2 + c) << 10;
      gld_lds16(s + off + lane * 16, d0 + off);
    }
  };
  auto stageV = [&](int ch, int buf) {
    char* d0 = (char*)&Vt[buf][0][0];
#pragma unroll
    for (int c = 0; c < 2; ++c) {
      int r0 = w * 16 + c * 8;             // 8 d-rows per call
      const char* s = (const char*)(Vh + (size_t)(r0 + (lane >> 3)) * Ll) +
                      ch * (KB2 * 2) + (lane & 7) * 16;
      gld_lds16(s, d0 + r0 * (KB2 * 2));
    }
  };
  auto stageM = [&](int ch) {
    mpre = *(const uint4*)(Mb + (size_t)mrow * Ll + ch * KB2 + mcol);
  };

  // ================= phase 1: exp row sums (scores bounded -> no max needed) ==========
  float rowsum[4] = {0.f, 0.f, 0.f, 0.f};
  stageK(0, 0); stageM(0);

  for (int ch = 0; ch < NB2; ++ch) {
    const int buf = ch & 1;
    asm volatile("s_waitcnt vmcnt(0)" ::: "memory");  // staged chunk landed
    __syncthreads();
    bool anym = __any((mpre.x | mpre.y | mpre.z | mpre.w) != 0u);
    if (ch + 1 < NB2) { stageK(ch + 1, buf ^ 1); stageM(ch + 1); }
    else              { stageK(0, 0); stageV(0, 0); stageM(0); }  // prestage phase 2
#pragma unroll
    for (int n0 = 0; n0 < KB2; n0 += 16) {
      s16x8 kf0 = *(const s16x8*)&Ks[buf][n0 + m][(quad * 8) ^ sw];
      s16x8 kf1 = *(const s16x8*)&Ks[buf][n0 + m][(32 + quad * 8) ^ sw];
      f32x4 c = {0.f, 0.f, 0.f, 0.f};
      c = __builtin_amdgcn_mfma_f32_16x16x32_bf16(qf[0], kf0, c, 0, 0, 0);
      c = __builtin_amdgcn_mfma_f32_16x16x32_bf16(qf[1], kf1, c, 0, 0, 0);
      if (!anym) {
#pragma unroll
        for (int r = 0; r < 4; ++r) rowsum[r] += exp2f(c[r] * EXPSC);
      } else {
        const unsigned char* mp =
            Mb + (size_t)(rowb + quad * 4) * Ll + ch * KB2 + n0 + m;
#pragma unroll
        for (int r = 0; r < 4; ++r) {
          float t = c[r] * EXPSC;
          if (mp[(size_t)r * Ll]) t = -1e9f;
          rowsum[r] += exp2f(t);
        }
      }
    }
  }
  // butterfly over the 16 lanes of each quad
#pragma unroll
  for (int off = 1; off < 16; off <<= 1) {
#pragma unroll
    for (int r = 0; r < 4; ++r) rowsum[r] += __shfl_xor(rowsum[r], off, 64);
  }
  float linv[4];
#pragma unroll
  for (int r = 0; r < 4; ++r) linv[r] = 1.0f / rowsum[r];

  // ================= phase 2: recompute, normalize, write attention, PV ===============
  f32x4 oacc[4];
  const f32x4 zero4 = {0.f, 0.f, 0.f, 0.f};
#pragma unroll
  for (int dt = 0; dt < 4; ++dt) oacc[dt] = zero4;

  for (int ch = 0; ch < NB2; ++ch) {
    const int buf = ch & 1;
    asm volatile("s_waitcnt vmcnt(0)" ::: "memory");
    __syncthreads();
    bool anym = __any((mpre.x | mpre.y | mpre.z | mpre.w) != 0u);
    if (ch + 1 < NB2) { stageK(ch + 1, buf ^ 1); stageV(ch + 1, buf ^ 1); stageM(ch + 1); }
#pragma unroll
    for (int g = 0; g < 2; ++g) {           // 32-key groups -> one PV k-step
      float pv[2][4];
#pragma unroll
      for (int sub = 0; sub < 2; ++sub) {
        const int n0 = g * 32 + sub * 16;
        s16x8 kf0 = *(const s16x8*)&Ks[buf][n0 + m][(quad * 8) ^ sw];
        s16x8 kf1 = *(const s16x8*)&Ks[buf][n0 + m][(32 + quad * 8) ^ sw];
        f32x4 c = {0.f, 0.f, 0.f, 0.f};
        c = __builtin_amdgcn_mfma_f32_16x16x32_bf16(qf[0], kf0, c, 0, 0, 0);
        c = __builtin_amdgcn_mfma_f32_16x16x32_bf16(qf[1], kf1, c, 0, 0, 0);
        if (!anym) {
#pragma unroll
          for (int r = 0; r < 4; ++r) {
            float p = exp2f(c[r] * EXPSC) * linv[r];
            pv[sub][r] = p;
            Pt[w][quad * 4 + r][sub * 16 + m] = f2bf(p);
          }
        } else {
          const unsigned char* mp =
              Mb + (size_t)(rowb + quad * 4) * Ll + ch * KB2 + n0 + m;
#pragma unroll
          for (int r = 0; r < 4; ++r) {
            float t = c[r] * EXPSC;
            if (mp[(size_t)r * Ll]) t = -1e9f;
            float p = exp2f(t) * linv[r];
            pv[sub][r] = p;
            Pt[w][quad * 4 + r][sub * 16 + m] = f2bf(p);
          }
        }
      }
      // wave-local LDS RAW: drain DS queue before A-layout reads
      asm volatile("s_waitcnt lgkmcnt(0)" ::: "memory");
      s16x8 pf = *(const s16x8*)&Pt[w][m][quad * 8];   // P[m][k=quad*8+j]
#pragma unroll
      for (int dt = 0; dt < 4; ++dt) {
        s16x8 vf = *(const s16x8*)&Vt[buf][dt * 16 + m][((g * 32) + quad * 8) ^ sw];
        oacc[dt] = __builtin_amdgcn_mfma_f32_16x16x32_bf16(pf, vf, oacc[dt], 0, 0, 0);
      }
      float* ap = att + (size_t)(rowb + quad * 4) * Ll + ch * KB2 + g * 32 + m;
#pragma unroll
      for (int r = 0; r < 4; ++r) {
        ap[(size_t)r * Ll]      = pv[0][r];
        ap[(size_t)r * Ll + 16] = pv[1][r];
      }
    }
  }

  // ---- epilogue: res[row][d], C layout row=quad*4+r col=m
#pragma unroll
  for (int r = 0; r < 4; ++r) {
    float* rp = res + (size_t)(rowb + quad * 4 + r) * Dd;
#pragma unroll
    for (int dt = 0; dt < 4; ++dt) rp[dt * 16 + m] = oacc[dt][r];
  }
}

// ===================== fallback (previous verified kernel, unchanged) =====================
static __device__ __forceinline__ void stage_K(const float* __restrict__ src,
                                               short (*Ksl)[72], int tid) {
#pragma unroll
  for (int it = 0; it < 8; ++it) {
    int idx4 = tid + it * 256;
    int n = idx4 >> 4;
    int d = (idx4 & 15) * 4;
    float4 v = *(const float4*)(src + n * Dd + d);
    short* dst = &Ksl[n][d];
    dst[0] = f2bf(v.x); dst[1] = f2bf(v.y);
    dst[2] = f2bf(v.z); dst[3] = f2bf(v.w);
  }
}

__global__ __launch_bounds__(256) void sdpa_fused(
    const float* __restrict__ Qg, const float* __restrict__ Kg,
    const float* __restrict__ Vg, const unsigned char* __restrict__ Mg,
    float* __restrict__ out) {
  __shared__ short Ks[KC][72];
  __shared__ short Vt[Dd][KC + 8];
  __shared__ short Pt[4][16][40];

  const int tid  = threadIdx.x;
  const int w    = tid >> 6;
  const int lane = tid & 63;
  const int m    = lane & 15;
  const int quad = lane >> 4;

  const int bh = blockIdx.x >> 5;
  const int qt = blockIdx.x & 31;
  const int b  = bh >> 4;
  const int q0 = qt * MT;

  const float* Qh = Qg + (size_t)bh * Ll * Dd;
  const float* Kh = Kg + (size_t)bh * Ll * Dd;
  const float* Vh = Vg + (size_t)bh * Ll * Dd;
  const unsigned char* Mb = Mg + (size_t)b * Ll * Ll;
  float* res = out + (size_t)bh * Ll * Dd;
  float* att = out + (size_t)Bb * Hh * Ll * Dd + (size_t)bh * Ll * Ll;

  const int rowb = q0 + w * 16;

  s16x8 qf[2];
  {
    const float* qp = Qh + (size_t)(rowb + m) * Dd + quad * 8;
#pragma unroll
    for (int s = 0; s < 2; ++s) {
      float4 a = *(const float4*)(qp + s * 32);
      float4 c = *(const float4*)(qp + s * 32 + 4);
      qf[s][0] = f2bf(a.x); qf[s][1] = f2bf(a.y);
      qf[s][2] = f2bf(a.z); qf[s][3] = f2bf(a.w);
      qf[s][4] = f2bf(c.x); qf[s][5] = f2bf(c.y);
      qf[s][6] = f2bf(c.z); qf[s][7] = f2bf(c.w);
    }
  }

  float rowsum[4] = {0.f, 0.f, 0.f, 0.f};
  for (int ch = 0; ch < NCH; ++ch) {
    __syncthreads();
    stage_K(Kh + (size_t)ch * KC * Dd, Ks, tid);
    __syncthreads();
#pragma unroll
    for (int n0 = 0; n0 < KC; n0 += 16) {
      s16x8 kf0 = *(const s16x8*)&Ks[n0 + m][quad * 8];
      s16x8 kf1 = *(const s16x8*)&Ks[n0 + m][32 + quad * 8];
      f32x4 c = {0.f, 0.f, 0.f, 0.f};
      c = __builtin_amdgcn_mfma_f32_16x16x32_bf16(qf[0], kf0, c, 0, 0, 0);
      c = __builtin_amdgcn_mfma_f32_16x16x32_bf16(qf[1], kf1, c, 0, 0, 0);
      const unsigned char* mp =
          Mb + (size_t)(rowb + quad * 4) * Ll + ch * KC + n0 + m;
#pragma unroll
      for (int r = 0; r < 4; ++r) {
        float s = c[r] * 0.125f;
        if (mp[(size_t)r * Ll]) s = -1e9f;
        rowsum[r] += __expf(s);
      }
    }
  }
#pragma unroll
  for (int off = 1; off < 16; off <<= 1) {
#pragma unroll
    for (int r = 0; r < 4; ++r) rowsum[r] += __shfl_xor(rowsum[r], off, 64);
  }
  float linv[4];
#pragma unroll
  for (int r = 0; r < 4; ++r) linv[r] = 1.0f / rowsum[r];

  f32x4 oacc[4];
  const f32x4 zero4 = {0.f, 0.f, 0.f, 0.f};
#pragma unroll
  for (int dt = 0; dt < 4; ++dt) oacc[dt] = zero4;

  for (int ch = 0; ch < NCH; ++ch) {
    __syncthreads();
    stage_K(Kh + (size_t)ch * KC * Dd, Ks, tid);
    {
      const float* src = Vh + (size_t)ch * KC * Dd;
      int d  = tid & 63;
      int kb = (tid >> 6) * 32;
#pragma unroll
      for (int p = 0; p < 4; ++p) {
        s16x8 pk;
#pragma unroll
        for (int j = 0; j < 8; ++j)
          pk[j] = f2bf(src[(size_t)(kb + p * 8 + j) * Dd + d]);
        *(s16x8*)&Vt[d][kb + p * 8] = pk;
      }
    }
    __syncthreads();
#pragma unroll
    for (int g = 0; g < 4; ++g) {
      float pv[2][4];
#pragma unroll
      for (int sub = 0; sub < 2; ++sub) {
        int n0 = g * 32 + sub * 16;
        s16x8 kf0 = *(const s16x8*)&Ks[n0 + m][quad * 8];
        s16x8 kf1 = *(const s16x8*)&Ks[n0 + m][32 + quad * 8];
        f32x4 c = {0.f, 0.f, 0.f, 0.f};
        c = __builtin_amdgcn_mfma_f32_16x16x32_bf16(qf[0], kf0, c, 0, 0, 0);
        c = __builtin_amdgcn_mfma_f32_16x16x32_bf16(qf[1], kf1, c, 0, 0, 0);
        const unsigned char* mp =
            Mb + (size_t)(rowb + quad * 4) * Ll + ch * KC + n0 + m;
#pragma unroll
        for (int r = 0; r < 4; ++r) {
          float s = c[r] * 0.125f;
          if (mp[(size_t)r * Ll]) s = -1e9f;
          float p = __expf(s) * linv[r];
          pv[sub][r] = p;
          Pt[w][quad * 4 + r][sub * 16 + m] = f2bf(p);
        }
      }
      asm volatile("s_waitcnt lgkmcnt(0)" ::: "memory");
      s16x8 pf = *(const s16x8*)&Pt[w][m][quad * 8];
#pragma unroll
      for (int dt = 0; dt < 4; ++dt) {
        s16x8 vf = *(const s16x8*)&Vt[dt * 16 + m][g * 32 + quad * 8];
        oacc[dt] = __builtin_amdgcn_mfma_f32_16x16x32_bf16(pf, vf, oacc[dt], 0, 0, 0);
      }
      float* ap = att + (size_t)(rowb + quad * 4) * Ll + ch * KC + g * 32 + m;
#pragma unroll
      for (int r = 0; r < 4; ++r) {
        ap[(size_t)r * Ll]      = pv[0][r];
        ap[(size_t)r * Ll + 16] = pv[1][r];
      }
    }
  }

#pragma unroll
  for (int r = 0; r < 4; ++r) {
    float* rp = res + (size_t)(rowb + quad * 4 + r) * Dd;
#pragma unroll
    for (int dt = 0; dt < 4; ++dt) rp[dt * 16 + m] = oacc[dt][r];
  }
}

extern "C" void kernel_launch(void* const* d_in, const int* in_sizes, int n_in,
                              void* d_out, int out_size, void* d_ws, size_t ws_size,
                              hipStream_t stream) {
  const float* Q = (const float*)d_in[0];
  const float* K = (const float*)d_in[1];
  const float* V = (const float*)d_in[2];
  const unsigned char* M = (const unsigned char*)d_in[3];
  float* out = (float*)d_out;

  const size_t half = (size_t)Bb * Hh * Ll * Dd * sizeof(short);  // 16 MiB each
  if (d_ws != nullptr && ws_size >= 2 * half) {
    short* Kb = (short*)d_ws;
    short* Vb = (short*)((char*)d_ws + half);
    hipLaunchKernelGGL(prep_k, dim3((Bb * Hh * Ll * Dd / 8) / 256), dim3(256), 0,
                       stream, K, Kb);
    hipLaunchKernelGGL(prep_v, dim3(Bb * Hh * (Ll / 64)), dim3(256), 0, stream, V, Vb);
    hipLaunchKernelGGL(sdpa_fused2, dim3(Bb * Hh * (Ll / MT)), dim3(256), 0, stream,
                       Q, Kb, Vb, M, out);
  } else {
    hipLaunchKernelGGL(sdpa_fused, dim3(Bb * Hh * (Ll / MT)), dim3(256), 0, stream,
                       Q, K, V, M, out);
  }
}